// Round 10
// baseline (22819.951 us; speedup 1.0000x reference)
//
#include <hip/hip_runtime.h>
#include <hip/hip_bf16.h>
#include <cstdint>
#include <cstddef>

#define T_STEPS 32768
#define DD 64
#define HH 128
#define GG 512   // 4*H

// d_out layout (float32, concatenated flat):
//   step (T,11) @0, experience (T,2) @360448, rsd (T,1) @425984, s (T,1) @458752
#define OFF_EXP 360448
#define OFF_RSD 425984
#define OFF_S   458752

typedef __attribute__((ext_vector_type(8))) _Float16 half8;
typedef __attribute__((ext_vector_type(4))) float f32x4;

__device__ __forceinline__ int   f2i(float x) { union { float f; int i; } u; u.f = x; return u.i; }
__device__ __forceinline__ float i2f(int x)   { union { int i; float f; } u; u.i = x; return u.f; }

__device__ __forceinline__ float exp2_f(float x) {
    float r; asm("v_exp_f32 %0, %1" : "=v"(r) : "v"(x)); return r;
}
__device__ __forceinline__ float sigm_fast(float x) {          // 1/(1+e^-x)
    return __builtin_amdgcn_rcpf(1.0f + exp2_f(x * -1.442695041f));
}
__device__ __forceinline__ float tanh_fast(float x) {          // 1 - 2/(1+e^2x)
    return __builtin_fmaf(
        __builtin_amdgcn_rcpf(1.0f + exp2_f(x * 2.885390082f)), -2.0f, 1.0f);
}
__device__ __forceinline__ unsigned packh2(float x, float y) {
    union { _Float16 h[2]; unsigned u; } c;
    c.h[0] = (_Float16)x; c.h[1] = (_Float16)y;
    return c.u;
}
// f16x2 dot with f32 accumulate, operands pinned to arch VGPRs
#define D2(acc, wreg, hreg) \
    asm("v_dot2_f32_f16 %0, %1, %2, %0" : "+v"(acc) : "v"(wreg), "v"(hreg))

// ---------------------------------------------------------------------------
// Kernel 1: pregate, permuted per-cell: P[r][4*cell + g] = pregate of gate g
// of cell (thread j computes W row grow = (j&3)*128 + (j>>2)).
// ---------------------------------------------------------------------------
__global__ __launch_bounds__(512, 2) void pregate_kernel(
    const float* __restrict__ X, const float* __restrict__ W_ih,
    const float* __restrict__ b_ih, const float* __restrict__ b_hh,
    float* __restrict__ P, int t0, int nrows)
{
    __shared__ __align__(16) float xs[DD];
    const int j = threadIdx.x;
    const int grow = (j & 3) * HH + (j >> 2);

    float w[DD];
    const float4* wv = reinterpret_cast<const float4*>(W_ih + (size_t)grow * DD);
#pragma unroll
    for (int k = 0; k < DD / 4; ++k) {
        float4 v = wv[k];
        w[4*k+0] = v.x; w[4*k+1] = v.y; w[4*k+2] = v.z; w[4*k+3] = v.w;
    }
    const float bias = b_ih[grow] + b_hh[grow];

    const int rpb = (nrows + gridDim.x - 1) / gridDim.x;
    const int r0  = blockIdx.x * rpb;
    const int r1  = (r0 + rpb < nrows) ? (r0 + rpb) : nrows;

    for (int r = r0; r < r1; ++r) {
        const int t = t0 + r;
        if (j < DD) xs[j] = X[(size_t)t * DD + j];
        __syncthreads();
        float acc = bias;
        const float4* xv = reinterpret_cast<const float4*>(xs);
#pragma unroll
        for (int k = 0; k < DD / 4; ++k) {
            float4 v = xv[k];
            acc += v.x*w[4*k+0] + v.y*w[4*k+1] + v.z*w[4*k+2] + v.w*w[4*k+3];
        }
        P[(size_t)r * GG + j] = acc;
        __syncthreads();
    }
}

// ---------------------------------------------------------------------------
// Kernel 2: sequential LSTM, 1 block x 512 threads = 8 waves (2/SIMD).
// ONE-HOP + K-SPLIT:
//   MFMA (K 0..64): tile mt = GATE TYPE; B col c0 = W row (mt*128+16w+c0);
//     4 gate-chains x 2 kt = 8 MFMA/wave (64 total). D rows replicated ->
//     lane (c0,kgrp) reg0 of chain gt = K[0,64)-sum of gate gt, cell 16w+c0.
//   dot2 (K 64..128, kgrp-sliced): lane covers 16 f16 at [64+16*kgrp, +16)
//     for its cell's 4 gates = 32 v_dot2. Combine slices using the kgrp
//     replication: ds_swizzle xor16 (intra-half) + ds_bpermute lane^32.
//   All lanes end with full sums for ONE cell -> uniform act + c/h update
//   (replicated x4 across kgrp). kgrp0 publishes h (f16 LDS), kgrp1 streams
//   hist. ONE raw barrier per step, single LDS hop (h publish->read).
// ---------------------------------------------------------------------------
__global__ __launch_bounds__(512, 2) void lstm_seq_kernel(
    const float* __restrict__ P, const float* __restrict__ W_hh,
    float* __restrict__ hist, float* __restrict__ state,
    int t0, int C)
{
    __shared__ __align__(16) _Float16 hh2[2][HH];

    const int j      = threadIdx.x;
    const int w      = j >> 6;       // wave 0..7
    const int l      = j & 63;
    const int c0     = l & 15;
    const int kgrp   = l >> 4;       // 0..3
    const int mycell = 16 * w + c0;
    const int bpaddr = (l ^ 32) << 2;   // ds_bpermute byte index: partner half

    // MFMA B fragments: wf[gt][kt][e] = W_hh[gt*128+mycell][32kt+8kgrp+e]
    half8 wf[4][2];
#pragma unroll
    for (int gt = 0; gt < 4; ++gt) {
        const float* wr = W_hh + (size_t)(gt * HH + mycell) * HH + 8 * kgrp;
#pragma unroll
        for (int kt = 0; kt < 2; ++kt) {
            const float* wp = wr + 32 * kt;
            float4 w0 = *reinterpret_cast<const float4*>(wp);
            float4 w1 = *reinterpret_cast<const float4*>(wp + 4);
            half8 hf;
            hf[0] = (_Float16)w0.x; hf[1] = (_Float16)w0.y;
            hf[2] = (_Float16)w0.z; hf[3] = (_Float16)w0.w;
            hf[4] = (_Float16)w1.x; hf[5] = (_Float16)w1.y;
            hf[6] = (_Float16)w1.z; hf[7] = (_Float16)w1.w;
            wf[gt][kt] = hf;
        }
    }

    // dot2 weights (K 64..128, own 16-slice): vw[gt][k] packed f16x2
    unsigned vw[4][8];
#pragma unroll
    for (int gt = 0; gt < 4; ++gt) {
        const float* wr = W_hh + (size_t)(gt * HH + mycell) * HH + 64 + 16 * kgrp;
#pragma unroll
        for (int k = 0; k < 8; ++k)
            vw[gt][k] = packh2(wr[2*k], wr[2*k+1]);
    }

    float c = 0.0f;
    if (t0 != 0) c = state[HH + mycell];           // replicated across kgrp
    if (j < HH) hh2[0][j] = (_Float16)((t0 != 0) ? state[j] : 0.0f);
    __syncthreads();

    const float* Pme = P + 4 * (size_t)mycell;     // this cell's i,f,g,o
    const f32x4 Z = {0.0f, 0.0f, 0.0f, 0.0f};
    f32x4 pc  = *reinterpret_cast<const f32x4*>(Pme);
    f32x4 pn1 = (C > 1) ? *reinterpret_cast<const f32x4*>(Pme + GG) : Z;
    const float* pp = Pme + 2 * (size_t)GG;
    float hn = 0.0f;

#pragma unroll 1
    for (int r = 0; r < C; ++r) {
        const int cur = r & 1;
        // MFMA A fragments (K 0..64): 2 broadcast ds_read_b128
        const _Float16* hb = &hh2[cur][8 * kgrp];
        const half8 a0 = *reinterpret_cast<const half8*>(hb);
        const half8 a1 = *reinterpret_cast<const half8*>(hb + 32);
        // dot2 h slice (16 f16): 2 broadcast b128 at [64+16*kgrp)
        const uint4* hvp = reinterpret_cast<const uint4*>(&hh2[cur][64 + 16 * kgrp]);
        const uint4 hv0 = hvp[0];
        const uint4 hv1 = hvp[1];

        // P prefetch 2 steps ahead (in flight across the raw barrier)
        f32x4 pn2 = Z;
        if (r + 2 < C) pn2 = *reinterpret_cast<const f32x4*>(pp);
        pp += GG;

#define MF(A, B, Cc) __builtin_amdgcn_mfma_f32_16x16x32_f16((A), (B), (Cc), 0, 0, 0)
        // 4 gate-chains x 2 kt (K 0..64)
        f32x4 qi = MF(a0, wf[0][0], Z);
        f32x4 qf = MF(a0, wf[1][0], Z);
        f32x4 qg = MF(a0, wf[2][0], Z);
        f32x4 qo = MF(a0, wf[3][0], Z);
        qi = MF(a1, wf[0][1], qi);
        qf = MF(a1, wf[1][1], qf);
        qg = MF(a1, wf[2][1], qg);
        qo = MF(a1, wf[3][1], qo);
#undef MF

        // dot2 (K 64..128 slice), 4 independent chains fill MFMA gaps
        float d0 = 0.f, d1 = 0.f, d2 = 0.f, d3 = 0.f;
        const unsigned hk[8] = {hv0.x, hv0.y, hv0.z, hv0.w,
                                hv1.x, hv1.y, hv1.z, hv1.w};
#pragma unroll
        for (int k = 0; k < 8; ++k) {
            D2(d0, vw[0][k], hk[k]);
            D2(d1, vw[1][k], hk[k]);
            D2(d2, vw[2][k], hk[k]);
            D2(d3, vw[3][k], hk[k]);
        }

        // combine kgrp slices: xor16 (intra 32-half) + lane^32 (bpermute)
        d0 += i2f(__builtin_amdgcn_ds_swizzle(f2i(d0), 0x401F));
        d1 += i2f(__builtin_amdgcn_ds_swizzle(f2i(d1), 0x401F));
        d2 += i2f(__builtin_amdgcn_ds_swizzle(f2i(d2), 0x401F));
        d3 += i2f(__builtin_amdgcn_ds_swizzle(f2i(d3), 0x401F));
        d0 += i2f(__builtin_amdgcn_ds_bpermute(bpaddr, f2i(d0)));
        d1 += i2f(__builtin_amdgcn_ds_bpermute(bpaddr, f2i(d1)));
        d2 += i2f(__builtin_amdgcn_ds_bpermute(bpaddr, f2i(d2)));
        d3 += i2f(__builtin_amdgcn_ds_bpermute(bpaddr, f2i(d3)));

        // uniform lane-local cell update (replicated x4 across kgrp)
        const float ai = sigm_fast(qi[0] + d0 + pc[0]);
        const float af = sigm_fast(qf[0] + d1 + pc[1]);
        const float ag = tanh_fast(qg[0] + d2 + pc[2]);
        const float ao = sigm_fast(qo[0] + d3 + pc[3]);
        c = __builtin_fmaf(af, c, ai * ag);
        hn = ao * tanh_fast(c);

        if (kgrp == 0)      hh2[cur ^ 1][mycell] = (_Float16)hn;
        else if (kgrp == 1) hist[(size_t)r * HH + mycell] = hn;

        pc = pn1; pn1 = pn2;

        // one raw barrier: drain LDS only, global loads stay in flight
        asm volatile("s_waitcnt lgkmcnt(0)" ::: "memory");
        __builtin_amdgcn_s_barrier();
        __builtin_amdgcn_sched_barrier(0);
    }

    if (kgrp == 0) {
        state[mycell]      = hn;
        state[HH + mycell] = c;
    }
}

// ---------------------------------------------------------------------------
// Kernel 3: heads, parallel over (t, output)
// ---------------------------------------------------------------------------
__global__ __launch_bounds__(256, 4) void heads_kernel(
    const float* __restrict__ hist,
    const float* __restrict__ W1, const float* __restrict__ b1,
    const float* __restrict__ W2, const float* __restrict__ b2,
    const float* __restrict__ W3, const float* __restrict__ b3,
    const float* __restrict__ W4, const float* __restrict__ b4,
    float* __restrict__ out, int t0, int C)
{
    const int idx = blockIdx.x * 256 + threadIdx.x;
    const int tr  = idx >> 4;
    const int oi  = idx & 15;
    if (tr >= C || oi >= 15) return;

    const float* wrow;
    float bias;
    if (oi < 11)       { wrow = W1 + oi * HH;        bias = b1[oi]; }
    else if (oi < 13)  { wrow = W2 + (oi - 11) * HH; bias = b2[oi - 11]; }
    else if (oi == 13) { wrow = W3;                  bias = b3[0]; }
    else               { wrow = W4;                  bias = b4[0]; }

    const float4* h4 = reinterpret_cast<const float4*>(hist + (size_t)tr * HH);
    const float4* w4 = reinterpret_cast<const float4*>(wrow);
    float s = bias;
#pragma unroll
    for (int k = 0; k < HH / 4; ++k) {
        float4 hv = h4[k];
        float4 wv = w4[k];
        s += hv.x*wv.x + hv.y*wv.y + hv.z*wv.z + hv.w*wv.w;
    }
    const int t = t0 + tr;
    if (oi < 11)       out[(size_t)t * 11 + oi] = s;
    else if (oi < 13)  out[OFF_EXP + (size_t)t * 2 + (oi - 11)] = s;
    else if (oi == 13) out[OFF_RSD + t] = s;
    else               out[OFF_S + t] = s;
}

// ---------------------------------------------------------------------------
extern "C" void kernel_launch(void* const* d_in, const int* in_sizes, int n_in,
                              void* d_out, int out_size, void* d_ws, size_t ws_size,
                              hipStream_t stream)
{
    const float* X    = (const float*)d_in[0];
    const float* W_ih = (const float*)d_in[1];
    const float* W_hh = (const float*)d_in[2];
    const float* b_ih = (const float*)d_in[3];
    const float* b_hh = (const float*)d_in[4];
    const float* W1   = (const float*)d_in[5];
    const float* b1   = (const float*)d_in[6];
    const float* W2   = (const float*)d_in[7];
    const float* b2   = (const float*)d_in[8];
    const float* W3   = (const float*)d_in[9];
    const float* b3   = (const float*)d_in[10];
    const float* W4   = (const float*)d_in[11];
    const float* b4   = (const float*)d_in[12];

    float* out   = (float*)d_out;
    float* state = (float*)d_ws;   // 256 floats: h then c

    // ws: state(1KB) | hist(C*128 f32) | P(C*512 f32)  => 2560 B/row
    size_t avail = (ws_size > 1024) ? (ws_size - 1024) / 2560 : 0;
    int C = (avail >= (size_t)T_STEPS) ? T_STEPS : (int)avail;
    if (C < 1) C = 1;
    float* hist = state + 256;
    float* P    = hist + (size_t)C * HH;

    for (int t0 = 0; t0 < T_STEPS; t0 += C) {
        const int Cc = (C < T_STEPS - t0) ? C : (T_STEPS - t0);
        const int nb = (Cc < 512) ? Cc : 512;
        pregate_kernel<<<nb, 512, 0, stream>>>(X, W_ih, b_ih, b_hh, P, t0, Cc);
        lstm_seq_kernel<<<1, 512, 0, stream>>>(P, W_hh, hist, state, t0, Cc);
        heads_kernel<<<(Cc * 16 + 255) / 256, 256, 0, stream>>>(
            hist, W1, b1, W2, b2, W3, b3, W4, b4, out, t0, Cc);
    }
}

// Round 11
// 16565.089 us; speedup vs baseline: 1.3776x; 1.3776x over previous
//
#include <hip/hip_runtime.h>
#include <hip/hip_bf16.h>
#include <cstdint>
#include <cstddef>

#define T_STEPS 32768
#define DD 64
#define HH 128
#define GG 512   // 4*H

// d_out layout (float32, concatenated flat):
//   step (T,11) @0, experience (T,2) @360448, rsd (T,1) @425984, s (T,1) @458752
#define OFF_EXP 360448
#define OFF_RSD 425984
#define OFF_S   458752

typedef __attribute__((ext_vector_type(8))) _Float16 half8;
typedef __attribute__((ext_vector_type(4))) float f32x4;

__device__ __forceinline__ float exp2_f(float x) {
    float r; asm("v_exp_f32 %0, %1" : "=v"(r) : "v"(x)); return r;
}

// Owned-gate permutation shared by pregate and the seq kernel:
// thread j (=64w+l) owns W_hh row grow(j) =
//   (j&3)*128 + (j>>6)*16 + ((j>>4)&3)*4 + ((j&15)>>2)
__device__ __forceinline__ int grow_of(int j) {
    return (j & 3) * HH + (j >> 6) * 16 + ((j >> 4) & 3) * 4 + ((j & 15) >> 2);
}

// ---------------------------------------------------------------------------
// Kernel 1: pregate, permuted: P[r][j] = pregate of row grow_of(j)
// ---------------------------------------------------------------------------
__global__ __launch_bounds__(512, 2) void pregate_kernel(
    const float* __restrict__ X, const float* __restrict__ W_ih,
    const float* __restrict__ b_ih, const float* __restrict__ b_hh,
    float* __restrict__ P, int t0, int nrows)
{
    __shared__ __align__(16) float xs[DD];
    const int j = threadIdx.x;
    const int grow = grow_of(j);

    float w[DD];
    const float4* wv = reinterpret_cast<const float4*>(W_ih + (size_t)grow * DD);
#pragma unroll
    for (int k = 0; k < DD / 4; ++k) {
        float4 v = wv[k];
        w[4*k+0] = v.x; w[4*k+1] = v.y; w[4*k+2] = v.z; w[4*k+3] = v.w;
    }
    const float bias = b_ih[grow] + b_hh[grow];

    const int rpb = (nrows + gridDim.x - 1) / gridDim.x;
    const int r0  = blockIdx.x * rpb;
    const int r1  = (r0 + rpb < nrows) ? (r0 + rpb) : nrows;

    for (int r = r0; r < r1; ++r) {
        const int t = t0 + r;
        if (j < DD) xs[j] = X[(size_t)t * DD + j];
        __syncthreads();
        float acc = bias;
        const float4* xv = reinterpret_cast<const float4*>(xs);
#pragma unroll
        for (int k = 0; k < DD / 4; ++k) {
            float4 v = xv[k];
            acc += v.x*w[4*k+0] + v.y*w[4*k+1] + v.z*w[4*k+2] + v.w*w[4*k+3];
        }
        P[(size_t)r * GG + j] = acc;
        __syncthreads();
    }
}

// ---------------------------------------------------------------------------
// Kernel 2: sequential LSTM, 1 block x 512 threads (8 waves), MFMA matvec.
//   A (mfma op0) = h replicated over 16 rows: lane reads 8 f16 at
//                  hh[32*kt + 8*kgrp] (broadcast ds_read_b128).
//   B (mfma op1) = W_hh columns: tile mt col (l&15) is W row
//                  lr = 16*mt + (l&15); gt = lr&3 = l&3, cell = 16w + (lr>>2).
//   D: cols = gates, rows replicated -> lane's acc[mt][0] = gate sum for
//      lr = 16*mt + (l&15). Lane owns lr = 16*kgrp + (l&15) (3-cndmask sel).
// Per step: 4 ds_read_b128 (h) + 16 MFMA + 1 act/lane + in-wave LDS
// redistribute + cell update on lanes 0..15 + ONE raw barrier.
// ---------------------------------------------------------------------------
__global__ __launch_bounds__(512, 2) void lstm_seq_kernel(
    const float* __restrict__ P, const float* __restrict__ W_hh,
    float* __restrict__ hist, float* __restrict__ state,
    int t0, int C)
{
    __shared__ __align__(16) _Float16 hh2[2][HH];
    __shared__ __align__(16) float gate_lds[GG];

    const int j    = threadIdx.x;
    const int w    = j >> 6;
    const int l    = j & 63;
    const int col  = l & 15;
    const int kgrp = l >> 4;     // 0..3
    const int gt   = l & 3;      // owned gate type: 0=i 1=f 2=g(tanh) 3=o

    // ---- B fragments: W_hh columns -> 64 packed f16 registers (AGPR-ok)
    half8 wf[4][4];
#pragma unroll
    for (int mt = 0; mt < 4; ++mt) {
        const int growB = gt * HH + 16 * w + 4 * mt + (col >> 2);
        const float* wr = W_hh + (size_t)growB * HH + 8 * kgrp;
#pragma unroll
        for (int kt = 0; kt < 4; ++kt) {
            const float* wp = wr + 32 * kt;
            float4 w0 = *reinterpret_cast<const float4*>(wp);
            float4 w1 = *reinterpret_cast<const float4*>(wp + 4);
            half8 hf;
            hf[0] = (_Float16)w0.x; hf[1] = (_Float16)w0.y;
            hf[2] = (_Float16)w0.z; hf[3] = (_Float16)w0.w;
            hf[4] = (_Float16)w1.x; hf[5] = (_Float16)w1.y;
            hf[6] = (_Float16)w1.z; hf[7] = (_Float16)w1.w;
            wf[mt][kt] = hf;
        }
    }

    // branch-free activation constants (R3/R4-verified formula)
    const bool  isg = (gt == 2);
    const float sA  = isg ?  2.885390082f : -1.442695041f;
    const float sB  = isg ? -2.0f : 1.0f;
    const float sC  = isg ?  1.0f : 0.0f;
    const bool  b0  = (kgrp & 1) != 0;
    const bool  b1  = (kgrp & 2) != 0;

    const int mycell = 16 * w + l;        // cell owned by lanes l<16
    float c = 0.0f;
    if (t0 != 0 && l < 16) c = state[HH + mycell];
    if (j < HH) hh2[0][j] = (_Float16)((t0 != 0) ? state[j] : 0.0f);
    __syncthreads();

    float pcq = P[j];
    float pn1 = (C > 1) ? P[GG + j] : 0.0f;
    const float* pp = P + 2 * (size_t)GG + j;
    float* hw = hist + mycell;
    float hn = 0.0f;
    const f32x4 Z = {0.0f, 0.0f, 0.0f, 0.0f};

#pragma unroll 1
    for (int r = 0; r < C; ++r) {
        // A fragments: h broadcast reads (4 x ds_read_b128)
        const _Float16* hb = &hh2[r & 1][8 * kgrp];
        const half8 a0 = *reinterpret_cast<const half8*>(hb);
        const half8 a1 = *reinterpret_cast<const half8*>(hb + 32);
        const half8 a2 = *reinterpret_cast<const half8*>(hb + 64);
        const half8 a3 = *reinterpret_cast<const half8*>(hb + 96);

        // P prefetch 2 steps ahead (stays in flight across the raw barrier)
        float pn2 = 0.0f;
        if (r + 2 < C) pn2 = *pp;
        pp += GG;

        // 16 MFMA: 4 independent kt-chains, C-in = constant zero vec
        f32x4 q0 = __builtin_amdgcn_mfma_f32_16x16x32_f16(a0, wf[0][0], Z, 0, 0, 0);
        f32x4 q1 = __builtin_amdgcn_mfma_f32_16x16x32_f16(a0, wf[1][0], Z, 0, 0, 0);
        f32x4 q2 = __builtin_amdgcn_mfma_f32_16x16x32_f16(a0, wf[2][0], Z, 0, 0, 0);
        f32x4 q3 = __builtin_amdgcn_mfma_f32_16x16x32_f16(a0, wf[3][0], Z, 0, 0, 0);
        q0 = __builtin_amdgcn_mfma_f32_16x16x32_f16(a1, wf[0][1], q0, 0, 0, 0);
        q1 = __builtin_amdgcn_mfma_f32_16x16x32_f16(a1, wf[1][1], q1, 0, 0, 0);
        q2 = __builtin_amdgcn_mfma_f32_16x16x32_f16(a1, wf[2][1], q2, 0, 0, 0);
        q3 = __builtin_amdgcn_mfma_f32_16x16x32_f16(a1, wf[3][1], q3, 0, 0, 0);
        q0 = __builtin_amdgcn_mfma_f32_16x16x32_f16(a2, wf[0][2], q0, 0, 0, 0);
        q1 = __builtin_amdgcn_mfma_f32_16x16x32_f16(a2, wf[1][2], q1, 0, 0, 0);
        q2 = __builtin_amdgcn_mfma_f32_16x16x32_f16(a2, wf[2][2], q2, 0, 0, 0);
        q3 = __builtin_amdgcn_mfma_f32_16x16x32_f16(a2, wf[3][2], q3, 0, 0, 0);
        q0 = __builtin_amdgcn_mfma_f32_16x16x32_f16(a3, wf[0][3], q0, 0, 0, 0);
        q1 = __builtin_amdgcn_mfma_f32_16x16x32_f16(a3, wf[1][3], q1, 0, 0, 0);
        q2 = __builtin_amdgcn_mfma_f32_16x16x32_f16(a3, wf[2][3], q2, 0, 0, 0);
        q3 = __builtin_amdgcn_mfma_f32_16x16x32_f16(a3, wf[3][3], q3, 0, 0, 0);

        // select owned gate sum: mt = kgrp (rows replicated -> reg 0)
        const float s01  = b0 ? q1[0] : q0[0];
        const float s23  = b0 ? q3[0] : q2[0];
        const float ssum = b1 ? s23 : s01;

        // activation (1 exp + 1 rcp per lane, branch-free)
        const float pre = ssum + pcq;
        const float t   = __builtin_amdgcn_rcpf(1.0f + exp2_f(pre * sA));
        const float a   = __builtin_fmaf(t, sB, sC);

        // in-wave redistribute: lr_own = 16*kgrp + col, region 64w..64w+64
        gate_lds[64 * w + 16 * kgrp + col] = a;
        asm volatile("s_waitcnt lgkmcnt(0)" ::: "memory");

        if (l < 16) {
            // gates (i,f,g,o) of cell 16w+l are 4 consecutive floats
            const f32x4 g4 = *reinterpret_cast<const f32x4*>(&gate_lds[64 * w + 4 * l]);
            c = __builtin_fmaf(g4[1], c, g4[0] * g4[2]);
            const float tc = __builtin_amdgcn_rcpf(1.0f + exp2_f(c * 2.885390082f));
            hn = g4[3] * __builtin_fmaf(tc, -2.0f, 1.0f);   // o * tanh(c)
            hh2[(r & 1) ^ 1][mycell] = (_Float16)hn;
            *hw = hn;                                        // heads input
        }
        hw += HH;
        pcq = pn1; pn1 = pn2;

        // single raw barrier: drain LDS only, P loads stay in flight
        asm volatile("s_waitcnt lgkmcnt(0)" ::: "memory");
        __builtin_amdgcn_s_barrier();
        __builtin_amdgcn_sched_barrier(0);
    }

    if (l < 16) {
        state[mycell]      = hn;
        state[HH + mycell] = c;
    }
}

// ---------------------------------------------------------------------------
// Kernel 3: heads, parallel over (t, output)
// ---------------------------------------------------------------------------
__global__ __launch_bounds__(256, 4) void heads_kernel(
    const float* __restrict__ hist,
    const float* __restrict__ W1, const float* __restrict__ b1,
    const float* __restrict__ W2, const float* __restrict__ b2,
    const float* __restrict__ W3, const float* __restrict__ b3,
    const float* __restrict__ W4, const float* __restrict__ b4,
    float* __restrict__ out, int t0, int C)
{
    const int idx = blockIdx.x * 256 + threadIdx.x;
    const int tr  = idx >> 4;
    const int oi  = idx & 15;
    if (tr >= C || oi >= 15) return;

    const float* wrow;
    float bias;
    if (oi < 11)       { wrow = W1 + oi * HH;        bias = b1[oi]; }
    else if (oi < 13)  { wrow = W2 + (oi - 11) * HH; bias = b2[oi - 11]; }
    else if (oi == 13) { wrow = W3;                  bias = b3[0]; }
    else               { wrow = W4;                  bias = b4[0]; }

    const float4* h4 = reinterpret_cast<const float4*>(hist + (size_t)tr * HH);
    const float4* w4 = reinterpret_cast<const float4*>(wrow);
    float s = bias;
#pragma unroll
    for (int k = 0; k < HH / 4; ++k) {
        float4 hv = h4[k];
        float4 wv = w4[k];
        s += hv.x*wv.x + hv.y*wv.y + hv.z*wv.z + hv.w*wv.w;
    }
    const int t = t0 + tr;
    if (oi < 11)       out[(size_t)t * 11 + oi] = s;
    else if (oi < 13)  out[OFF_EXP + (size_t)t * 2 + (oi - 11)] = s;
    else if (oi == 13) out[OFF_RSD + t] = s;
    else               out[OFF_S + t] = s;
}

// ---------------------------------------------------------------------------
extern "C" void kernel_launch(void* const* d_in, const int* in_sizes, int n_in,
                              void* d_out, int out_size, void* d_ws, size_t ws_size,
                              hipStream_t stream)
{
    const float* X    = (const float*)d_in[0];
    const float* W_ih = (const float*)d_in[1];
    const float* W_hh = (const float*)d_in[2];
    const float* b_ih = (const float*)d_in[3];
    const float* b_hh = (const float*)d_in[4];
    const float* W1   = (const float*)d_in[5];
    const float* b1   = (const float*)d_in[6];
    const float* W2   = (const float*)d_in[7];
    const float* b2   = (const float*)d_in[8];
    const float* W3   = (const float*)d_in[9];
    const float* b3   = (const float*)d_in[10];
    const float* W4   = (const float*)d_in[11];
    const float* b4   = (const float*)d_in[12];

    float* out   = (float*)d_out;
    float* state = (float*)d_ws;   // 256 floats: h then c

    // ws: state(1KB) | hist(C*128 f32) | P(C*512 f32)  => 2560 B/row
    size_t avail = (ws_size > 1024) ? (ws_size - 1024) / 2560 : 0;
    int C = (avail >= (size_t)T_STEPS) ? T_STEPS : (int)avail;
    if (C < 1) C = 1;
    float* hist = state + 256;
    float* P    = hist + (size_t)C * HH;

    for (int t0 = 0; t0 < T_STEPS; t0 += C) {
        const int Cc = (C < T_STEPS - t0) ? C : (T_STEPS - t0);
        const int nb = (Cc < 512) ? Cc : 512;
        pregate_kernel<<<nb, 512, 0, stream>>>(X, W_ih, b_ih, b_hh, P, t0, Cc);
        lstm_seq_kernel<<<1, 512, 0, stream>>>(P, W_hh, hist, state, t0, Cc);
        heads_kernel<<<(Cc * 16 + 255) / 256, 256, 0, stream>>>(
            hist, W1, b1, W2, b2, W3, b3, W4, b4, out, t0, Cc);
    }
}

// Round 12
// 16433.916 us; speedup vs baseline: 1.3886x; 1.0080x over previous
//
#include <hip/hip_runtime.h>
#include <hip/hip_bf16.h>
#include <cstdint>
#include <cstddef>

#define T_STEPS 32768
#define DD 64
#define HH 128
#define GG 512   // 4*H

// d_out layout (float32, concatenated flat):
//   step (T,11) @0, experience (T,2) @360448, rsd (T,1) @425984, s (T,1) @458752
#define OFF_EXP 360448
#define OFF_RSD 425984
#define OFF_S   458752

typedef __attribute__((ext_vector_type(8))) _Float16 half8;
typedef __attribute__((ext_vector_type(4))) float f32x4;

__device__ __forceinline__ int   f2i(float x) { union { float f; int i; } u; u.f = x; return u.i; }
__device__ __forceinline__ float i2f(int x)   { union { int i; float f; } u; u.i = x; return u.f; }

// quad_perm cross-lane move via DPP (pure VALU, no LDS pipe) — R3-verified
template<int CTRL>
__device__ __forceinline__ float qdpp(float v) {
    return i2f(__builtin_amdgcn_mov_dpp(f2i(v), CTRL, 0xf, 0xf, true));
}
#define QP_BC0 0x00
#define QP_BC1 0x55
#define QP_BC2 0xAA
#define QP_BC3 0xFF

__device__ __forceinline__ float exp2_f(float x) {
    float r; asm("v_exp_f32 %0, %1" : "=v"(r) : "v"(x)); return r;
}

// Owned-gate permutation shared by pregate and the seq kernel:
// thread j (=64w+l) owns W_hh row grow(j) = (j&3)*128 + mycell(j), where
// mycell(j) = (j>>6)*16 + ((j>>4)&3)*4 + ((j&15)>>2). The 4 gates of a cell
// sit in the 4 lanes of one quad (gate = l&3).
__device__ __forceinline__ int grow_of(int j) {
    return (j & 3) * HH + (j >> 6) * 16 + ((j >> 4) & 3) * 4 + ((j & 15) >> 2);
}

// ---------------------------------------------------------------------------
// Kernel 1: pregate, permuted: P[r][j] = pregate of row grow_of(j)
// ---------------------------------------------------------------------------
__global__ __launch_bounds__(512, 2) void pregate_kernel(
    const float* __restrict__ X, const float* __restrict__ W_ih,
    const float* __restrict__ b_ih, const float* __restrict__ b_hh,
    float* __restrict__ P, int t0, int nrows)
{
    __shared__ __align__(16) float xs[DD];
    const int j = threadIdx.x;
    const int grow = grow_of(j);

    float w[DD];
    const float4* wv = reinterpret_cast<const float4*>(W_ih + (size_t)grow * DD);
#pragma unroll
    for (int k = 0; k < DD / 4; ++k) {
        float4 v = wv[k];
        w[4*k+0] = v.x; w[4*k+1] = v.y; w[4*k+2] = v.z; w[4*k+3] = v.w;
    }
    const float bias = b_ih[grow] + b_hh[grow];

    const int rpb = (nrows + gridDim.x - 1) / gridDim.x;
    const int r0  = blockIdx.x * rpb;
    const int r1  = (r0 + rpb < nrows) ? (r0 + rpb) : nrows;

    for (int r = r0; r < r1; ++r) {
        const int t = t0 + r;
        if (j < DD) xs[j] = X[(size_t)t * DD + j];
        __syncthreads();
        float acc = bias;
        const float4* xv = reinterpret_cast<const float4*>(xs);
#pragma unroll
        for (int k = 0; k < DD / 4; ++k) {
            float4 v = xv[k];
            acc += v.x*w[4*k+0] + v.y*w[4*k+1] + v.z*w[4*k+2] + v.w*w[4*k+3];
        }
        P[(size_t)r * GG + j] = acc;
        __syncthreads();
    }
}

// ---------------------------------------------------------------------------
// Kernel 2: sequential LSTM, 1 block x 512 threads (8 waves), MFMA matvec
// (identical to the R5 structure) + QUAD-DPP gate exchange (replaces the
// gate-LDS turnaround):
//   A (mfma op0) = h replicated over 16 rows (4 broadcast ds_read_b128)
//   B (mfma op1) = W_hh columns: tile mt col c = W row (c&3)*128+16w+4mt+(c>>2)
//   Lane (col,kgrp) selects tile mt=kgrp, reg0 -> its owned gate (col&3) of
//   cell mycell = 16w+4*kgrp+(col>>2). The quad's 4 lanes hold the 4 gates of
//   mycell -> 4 quad_perm DPP movs gather (ai,af,ag,ao); c/h update runs on
//   ALL lanes (replicated x4 per cell, no divergence, no LDS hop).
//   gt==0 lane publishes h (f16 LDS), gt==1 lane streams hist.
// Per step: 4 ds_read_b128 + 16 MFMA + 1 act/lane + 4 DPP + update +
// 1 ds_write_b16 + ONE raw barrier. Zero gate-LDS traffic.
// ---------------------------------------------------------------------------
__global__ __launch_bounds__(512, 2) void lstm_seq_kernel(
    const float* __restrict__ P, const float* __restrict__ W_hh,
    float* __restrict__ hist, float* __restrict__ state,
    int t0, int C)
{
    __shared__ __align__(16) _Float16 hh2[2][HH];

    const int j    = threadIdx.x;
    const int w    = j >> 6;
    const int l    = j & 63;
    const int col  = l & 15;
    const int kgrp = l >> 4;     // 0..3
    const int gt   = l & 3;      // owned gate type: 0=i 1=f 2=g(tanh) 3=o
    const int mycell = 16 * w + 4 * kgrp + (col >> 2);   // quad-owned cell

    // ---- B fragments: W_hh columns -> 64 packed f16 registers (AGPR-ok)
    half8 wf[4][4];
#pragma unroll
    for (int mt = 0; mt < 4; ++mt) {
        const int growB = gt * HH + 16 * w + 4 * mt + (col >> 2);
        const float* wr = W_hh + (size_t)growB * HH + 8 * kgrp;
#pragma unroll
        for (int kt = 0; kt < 4; ++kt) {
            const float* wp = wr + 32 * kt;
            float4 w0 = *reinterpret_cast<const float4*>(wp);
            float4 w1 = *reinterpret_cast<const float4*>(wp + 4);
            half8 hf;
            hf[0] = (_Float16)w0.x; hf[1] = (_Float16)w0.y;
            hf[2] = (_Float16)w0.z; hf[3] = (_Float16)w0.w;
            hf[4] = (_Float16)w1.x; hf[5] = (_Float16)w1.y;
            hf[6] = (_Float16)w1.z; hf[7] = (_Float16)w1.w;
            wf[mt][kt] = hf;
        }
    }

    // branch-free activation constants (R3/R4-verified formula)
    const bool  isg = (gt == 2);
    const float sA  = isg ?  2.885390082f : -1.442695041f;
    const float sB  = isg ? -2.0f : 1.0f;
    const float sC  = isg ?  1.0f : 0.0f;
    const bool  b0  = (kgrp & 1) != 0;
    const bool  b1  = (kgrp & 2) != 0;

    float c = 0.0f;
    if (t0 != 0) c = state[HH + mycell];            // replicated across quad
    if (j < HH) hh2[0][j] = (_Float16)((t0 != 0) ? state[j] : 0.0f);
    __syncthreads();

    float pcq = P[j];
    float pn1 = (C > 1) ? P[GG + j] : 0.0f;
    const float* pp = P + 2 * (size_t)GG + j;
    float hn = 0.0f;
    const f32x4 Z = {0.0f, 0.0f, 0.0f, 0.0f};

#pragma unroll 1
    for (int r = 0; r < C; ++r) {
        // A fragments: h broadcast reads (4 x ds_read_b128)
        const _Float16* hb = &hh2[r & 1][8 * kgrp];
        const half8 a0 = *reinterpret_cast<const half8*>(hb);
        const half8 a1 = *reinterpret_cast<const half8*>(hb + 32);
        const half8 a2 = *reinterpret_cast<const half8*>(hb + 64);
        const half8 a3 = *reinterpret_cast<const half8*>(hb + 96);

        // P prefetch 2 steps ahead (stays in flight across the raw barrier)
        float pn2 = 0.0f;
        if (r + 2 < C) pn2 = *pp;
        pp += GG;

        // 16 MFMA: 4 independent kt-chains, C-in = constant zero vec
        f32x4 q0 = __builtin_amdgcn_mfma_f32_16x16x32_f16(a0, wf[0][0], Z, 0, 0, 0);
        f32x4 q1 = __builtin_amdgcn_mfma_f32_16x16x32_f16(a0, wf[1][0], Z, 0, 0, 0);
        f32x4 q2 = __builtin_amdgcn_mfma_f32_16x16x32_f16(a0, wf[2][0], Z, 0, 0, 0);
        f32x4 q3 = __builtin_amdgcn_mfma_f32_16x16x32_f16(a0, wf[3][0], Z, 0, 0, 0);
        q0 = __builtin_amdgcn_mfma_f32_16x16x32_f16(a1, wf[0][1], q0, 0, 0, 0);
        q1 = __builtin_amdgcn_mfma_f32_16x16x32_f16(a1, wf[1][1], q1, 0, 0, 0);
        q2 = __builtin_amdgcn_mfma_f32_16x16x32_f16(a1, wf[2][1], q2, 0, 0, 0);
        q3 = __builtin_amdgcn_mfma_f32_16x16x32_f16(a1, wf[3][1], q3, 0, 0, 0);
        q0 = __builtin_amdgcn_mfma_f32_16x16x32_f16(a2, wf[0][2], q0, 0, 0, 0);
        q1 = __builtin_amdgcn_mfma_f32_16x16x32_f16(a2, wf[1][2], q1, 0, 0, 0);
        q2 = __builtin_amdgcn_mfma_f32_16x16x32_f16(a2, wf[2][2], q2, 0, 0, 0);
        q3 = __builtin_amdgcn_mfma_f32_16x16x32_f16(a2, wf[3][2], q3, 0, 0, 0);
        q0 = __builtin_amdgcn_mfma_f32_16x16x32_f16(a3, wf[0][3], q0, 0, 0, 0);
        q1 = __builtin_amdgcn_mfma_f32_16x16x32_f16(a3, wf[1][3], q1, 0, 0, 0);
        q2 = __builtin_amdgcn_mfma_f32_16x16x32_f16(a3, wf[2][3], q2, 0, 0, 0);
        q3 = __builtin_amdgcn_mfma_f32_16x16x32_f16(a3, wf[3][3], q3, 0, 0, 0);

        // select owned gate sum: tile mt = kgrp (rows replicated -> reg 0)
        const float s01  = b0 ? q1[0] : q0[0];
        const float s23  = b0 ? q3[0] : q2[0];
        const float ssum = b1 ? s23 : s01;

        // activation (1 exp + 1 rcp per lane, branch-free)
        const float pre = ssum + pcq;
        const float t   = __builtin_amdgcn_rcpf(1.0f + exp2_f(pre * sA));
        const float a   = __builtin_fmaf(t, sB, sC);

        // quad-DPP gather: quad lane g holds activated gate g of mycell
        const float ai = qdpp<QP_BC0>(a);
        const float af = qdpp<QP_BC1>(a);
        const float ag = qdpp<QP_BC2>(a);
        const float ao = qdpp<QP_BC3>(a);

        // lane-local cell update, replicated x4 across the quad
        c = __builtin_fmaf(af, c, ai * ag);
        const float tc = __builtin_amdgcn_rcpf(1.0f + exp2_f(c * 2.885390082f));
        hn = ao * __builtin_fmaf(tc, -2.0f, 1.0f);   // o * tanh(c)

        if (gt == 0)      hh2[(r & 1) ^ 1][mycell] = (_Float16)hn;
        else if (gt == 1) hist[(size_t)r * HH + mycell] = hn;

        pcq = pn1; pn1 = pn2;

        // single raw barrier: drain LDS only, P loads stay in flight
        asm volatile("s_waitcnt lgkmcnt(0)" ::: "memory");
        __builtin_amdgcn_s_barrier();
        __builtin_amdgcn_sched_barrier(0);
    }

    if (gt == 0) {
        state[mycell]      = hn;
        state[HH + mycell] = c;
    }
}

// ---------------------------------------------------------------------------
// Kernel 3: heads, parallel over (t, output)
// ---------------------------------------------------------------------------
__global__ __launch_bounds__(256, 4) void heads_kernel(
    const float* __restrict__ hist,
    const float* __restrict__ W1, const float* __restrict__ b1,
    const float* __restrict__ W2, const float* __restrict__ b2,
    const float* __restrict__ W3, const float* __restrict__ b3,
    const float* __restrict__ W4, const float* __restrict__ b4,
    float* __restrict__ out, int t0, int C)
{
    const int idx = blockIdx.x * 256 + threadIdx.x;
    const int tr  = idx >> 4;
    const int oi  = idx & 15;
    if (tr >= C || oi >= 15) return;

    const float* wrow;
    float bias;
    if (oi < 11)       { wrow = W1 + oi * HH;        bias = b1[oi]; }
    else if (oi < 13)  { wrow = W2 + (oi - 11) * HH; bias = b2[oi - 11]; }
    else if (oi == 13) { wrow = W3;                  bias = b3[0]; }
    else               { wrow = W4;                  bias = b4[0]; }

    const float4* h4 = reinterpret_cast<const float4*>(hist + (size_t)tr * HH);
    const float4* w4 = reinterpret_cast<const float4*>(wrow);
    float s = bias;
#pragma unroll
    for (int k = 0; k < HH / 4; ++k) {
        float4 hv = h4[k];
        float4 wv = w4[k];
        s += hv.x*wv.x + hv.y*wv.y + hv.z*wv.z + hv.w*wv.w;
    }
    const int t = t0 + tr;
    if (oi < 11)       out[(size_t)t * 11 + oi] = s;
    else if (oi < 13)  out[OFF_EXP + (size_t)t * 2 + (oi - 11)] = s;
    else if (oi == 13) out[OFF_RSD + t] = s;
    else               out[OFF_S + t] = s;
}

// ---------------------------------------------------------------------------
extern "C" void kernel_launch(void* const* d_in, const int* in_sizes, int n_in,
                              void* d_out, int out_size, void* d_ws, size_t ws_size,
                              hipStream_t stream)
{
    const float* X    = (const float*)d_in[0];
    const float* W_ih = (const float*)d_in[1];
    const float* W_hh = (const float*)d_in[2];
    const float* b_ih = (const float*)d_in[3];
    const float* b_hh = (const float*)d_in[4];
    const float* W1   = (const float*)d_in[5];
    const float* b1   = (const float*)d_in[6];
    const float* W2   = (const float*)d_in[7];
    const float* b2   = (const float*)d_in[8];
    const float* W3   = (const float*)d_in[9];
    const float* b3   = (const float*)d_in[10];
    const float* W4   = (const float*)d_in[11];
    const float* b4   = (const float*)d_in[12];

    float* out   = (float*)d_out;
    float* state = (float*)d_ws;   // 256 floats: h then c

    // ws: state(1KB) | hist(C*128 f32) | P(C*512 f32)  => 2560 B/row
    size_t avail = (ws_size > 1024) ? (ws_size - 1024) / 2560 : 0;
    int C = (avail >= (size_t)T_STEPS) ? T_STEPS : (int)avail;
    if (C < 1) C = 1;
    float* hist = state + 256;
    float* P    = hist + (size_t)C * HH;

    for (int t0 = 0; t0 < T_STEPS; t0 += C) {
        const int Cc = (C < T_STEPS - t0) ? C : (T_STEPS - t0);
        const int nb = (Cc < 512) ? Cc : 512;
        pregate_kernel<<<nb, 512, 0, stream>>>(X, W_ih, b_ih, b_hh, P, t0, Cc);
        lstm_seq_kernel<<<1, 512, 0, stream>>>(P, W_hh, hist, state, t0, Cc);
        heads_kernel<<<(Cc * 16 + 255) / 256, 256, 0, stream>>>(
            hist, W1, b1, W2, b2, W3, b3, W4, b4, out, t0, Cc);
    }
}